// Round 5
// baseline (811.515 us; speedup 1.0000x reference)
//
#include <hip/hip_runtime.h>
#include <hip/hip_bf16.h>
#include <math.h>

// Problem constants: B=4, N=4096, D=1024, H=16, HD=64, MLP=4096
#define NTOK   16384      // B*N rows
#define DMODEL 1024
#define DMLP   4096

typedef __attribute__((ext_vector_type(8))) __bf16  bf16x8;
typedef __attribute__((ext_vector_type(4))) float   f32x4;
typedef __attribute__((ext_vector_type(8))) unsigned short u16x8;
typedef __attribute__((ext_vector_type(4))) unsigned int   u32x4;

__device__ __forceinline__ float bf2f(unsigned short u) {
  unsigned int i = ((unsigned int)u) << 16;
  return __builtin_bit_cast(float, i);
}
__device__ __forceinline__ unsigned short f2bf(float f) {
  unsigned int u = __builtin_bit_cast(unsigned int, f);
  unsigned int r = 0x7fffu + ((u >> 16) & 1u);
  return (unsigned short)((u + r) >> 16);
}

__device__ __forceinline__ void gload_lds16(const void* g, void* l) {
  __builtin_amdgcn_global_load_lds(
      (const __attribute__((address_space(1))) unsigned int*)g,
      (__attribute__((address_space(3))) unsigned int*)l, 16, 0, 0);
}

__device__ __forceinline__ float gelu_f(float x) {
  float u = 1.5957691216057308f * (x + 0.044715f * x * x * x);
  return x / (1.f + __expf(-u));
}

// attn-output column permutation: c = g(2):r(2):t(2):i(4) -> c' = g:i:r:t
__device__ __forceinline__ int permc(int k) {
  return (k & 0x300) | ((k & 15) << 4) | (((k >> 6) & 3) << 2) | ((k >> 4) & 3);
}
// qkv k/v-block column permutation: n = h*64+d -> n' = d*16+h  (within 1024 block)
__device__ __forceinline__ int kvperm(int n) {
  return ((n & 63) << 4) | ((n >> 6) & 15);
}

// ---------------- weight transpose + f32->bf16 -------------------------------
// PERM: 0 none; 1 = permc on K index (wo); 2 = kvperm on N index (wk/wv)
template<int PERM>
__global__ void __launch_bounds__(256) transpose_cvt(
    const float* __restrict__ W, unsigned short* __restrict__ Wt, int K, int N)
{
  __shared__ float tile[32][33];
  const int kb = blockIdx.y * 32, nb = blockIdx.x * 32;
  const int tx = threadIdx.x & 31, ty = threadIdx.x >> 5;   // 32 x 8
#pragma unroll
  for (int j = 0; j < 32; j += 8)
    tile[ty + j][tx] = W[(size_t)(kb + ty + j) * N + nb + tx];
  __syncthreads();
  const int kw = (PERM == 1) ? permc(kb + tx) : (kb + tx);
#pragma unroll
  for (int j = 0; j < 32; j += 8) {
    const int n  = nb + ty + j;
    const int nw = (PERM == 2) ? kvperm(n) : n;
    Wt[(size_t)nw * K + kw] = f2bf(tile[tx][ty + j]);
  }
}

__global__ void __launch_bounds__(256) concat_bias(
    const float* __restrict__ bq, const float* __restrict__ bk,
    const float* __restrict__ bv, float* __restrict__ bqkv)
{
  const int i = blockIdx.x * 256 + threadIdx.x;   // grid 12 -> 3072
  if (i < 1024)      bqkv[i] = bq[i];
  else if (i < 2048) bqkv[1024 + kvperm(i - 1024)] = bk[i - 1024];
  else               bqkv[2048 + kvperm(i - 2048)] = bv[i - 2048];
}

// ---------------- LayerNorm (biased var, eps=1e-5) -> bf16 -------------------
__global__ void __launch_bounds__(256) ln_kernel(
    const float* __restrict__ x, const float* __restrict__ w,
    const float* __restrict__ b, unsigned short* __restrict__ out)
{
  const int row = blockIdx.x;
  const int t = threadIdx.x;
  const float4 v = ((const float4*)(x + (size_t)row * DMODEL))[t];
  float s  = v.x + v.y + v.z + v.w;
  float s2 = v.x*v.x + v.y*v.y + v.z*v.z + v.w*v.w;
#pragma unroll
  for (int o = 1; o < 64; o <<= 1) { s += __shfl_xor(s, o); s2 += __shfl_xor(s2, o); }
  __shared__ float red[8];
  const int wid = t >> 6;
  if ((t & 63) == 0) { red[wid] = s; red[4 + wid] = s2; }
  __syncthreads();
  s  = red[0] + red[1] + red[2] + red[3];
  s2 = red[4] + red[5] + red[6] + red[7];
  const float mean = s * (1.f / DMODEL);
  const float rstd = rsqrtf(s2 * (1.f / DMODEL) - mean * mean + 1e-5f);
  const float4 wv = ((const float4*)w)[t];
  const float4 bv = ((const float4*)b)[t];
  ushort4 o;
  o.x = f2bf((v.x - mean) * rstd * wv.x + bv.x);
  o.y = f2bf((v.y - mean) * rstd * wv.y + bv.y);
  o.z = f2bf((v.z - mean) * rstd * wv.z + bv.z);
  o.w = f2bf((v.w - mean) * rstd * wv.w + bv.w);
  ((ushort4*)(out + (size_t)row * DMODEL))[t] = o;
}

// ---------------- 256x256 8-phase bf16 MFMA GEMM -----------------------------
// Identical schedule to the verified round-2/4 kernel; ONLY the wg->tile
// mapping changed: XCD chunk + 4x4 super-tile so 16 consecutive wg on one XCD
// touch A 2MB + B 2MB (= one XCD L2) instead of streaming B per m-row.
// Requires tiles_m%4==0, tiles_n%4==0, nwg%8==0, cpx%16==0 (true for all
// shapes here: FC 64x16/128, QKV 64x12/96, WO+PROJ 64x4/32).
template<int MODE>
__global__ void __launch_bounds__(512, 2) gemm256(
    const unsigned short* __restrict__ A, const unsigned short* __restrict__ Bt,
    int M, int N, int K,
    const float* __restrict__ bias, const float* __restrict__ addsrc,
    void* __restrict__ outp)
{
  extern __shared__ unsigned short lds[];   // 65536 shorts = 128 KiB
  const int t    = threadIdx.x;
  const int lane = t & 63;
  const int wid  = t >> 6;
  const int wm   = wid >> 2;     // 0..1
  const int wn   = wid & 3;      // 0..3
  const int fr   = lane & 15;
  const int hi   = lane >> 4;    // 0..3

  const int tiles_n = N >> 8;
  const int nwg = (int)gridDim.x;
  const int cpx = nwg >> 3;
  const int bid = (int)blockIdx.x;
  const int wg  = (bid & 7) * cpx + (bid >> 3);   // XCD-chunked
  // 4x4 super-tile within the chunk
  const int grp = wg >> 4, in16 = wg & 15;
  const int gpr = tiles_n >> 2;
  const int mt  = (grp / gpr) * 4 + (in16 >> 2);
  const int nt  = (grp % gpr) * 4 + (in16 & 3);
  const int m0 = mt << 8;
  const int n0 = nt << 8;

  const int srow0 = t >> 3;
  const int srow1 = srow0 + 64;
  const int sc    = t & 7;
  const size_t soff0 = (size_t)srow0 * K + (size_t)((sc ^ (srow0 & 7)) << 3);
  const size_t soff1 = (size_t)srow1 * K + (size_t)((sc ^ (srow1 & 7)) << 3);
  const unsigned short* Ag = A  + (size_t)m0 * K;
  const unsigned short* Bg = Bt + (size_t)n0 * K;

  const int pc0 = hi ^ (fr & 7);         // ks=0 chunk
  const int pc1 = (4 + hi) ^ (fr & 7);   // ks=1 chunk

  f32x4  acc[8][4] = {};
  bf16x8 af[4][2];
  bf16x8 bfr[4][2];

#define STAGE(gptr, ro) do { \
    gload_lds16((gptr) + soff0, lds + (ro) + t*8); \
    gload_lds16((gptr) + soff1, lds + (ro) + 4096 + t*8); \
  } while(0)

#define LDA_(buf, mh) do { \
    const unsigned short* p_ = lds + (buf)*16384 + wm*8192 + (mh)*4096 + fr*64; \
    _Pragma("unroll") for (int i = 0; i < 4; ++i) { \
      af[i][0] = *(const bf16x8*)(p_ + i*1024 + pc0*8); \
      af[i][1] = *(const bf16x8*)(p_ + i*1024 + pc1*8); } \
  } while(0)

#define LDB_(buf, nh) do { \
    const unsigned short* p_ = lds + 32768 + (buf)*16384 + (wn>>1)*8192 + (wn&1)*4096 + fr*64; \
    _Pragma("unroll") for (int jj = 0; jj < 2; ++jj) { \
      bfr[(nh)*2+jj][0] = *(const bf16x8*)(p_ + ((nh)*2+jj)*1024 + pc0*8); \
      bfr[(nh)*2+jj][1] = *(const bf16x8*)(p_ + ((nh)*2+jj)*1024 + pc1*8); } \
  } while(0)

#define MMA_(mh, nh) do { \
    __builtin_amdgcn_s_setprio(1); \
    _Pragma("unroll") for (int i = 0; i < 4; ++i) \
      _Pragma("unroll") for (int jj = 0; jj < 2; ++jj) { \
        acc[(mh)*4+i][(nh)*2+jj] = __builtin_amdgcn_mfma_f32_16x16x32_bf16(af[i][0], bfr[(nh)*2+jj][0], acc[(mh)*4+i][(nh)*2+jj], 0,0,0); \
        acc[(mh)*4+i][(nh)*2+jj] = __builtin_amdgcn_mfma_f32_16x16x32_bf16(af[i][1], bfr[(nh)*2+jj][1], acc[(mh)*4+i][(nh)*2+jj], 0,0,0); } \
    __builtin_amdgcn_s_setprio(0); \
  } while(0)

#define GBAR() __builtin_amdgcn_s_barrier()

  const size_t HSTR = (size_t)128 * K;
  const int NT = K >> 6;
  const int R  = NT >> 1;

  STAGE(Ag,               0);
  STAGE(Ag + HSTR,        8192);
  STAGE(Bg,               32768);
  STAGE(Bg + HSTR,        32768 + 8192);
  STAGE(Bg + 64,          32768 + 16384);
  STAGE(Bg + HSTR + 64,   32768 + 16384 + 8192);
  asm volatile("s_waitcnt vmcnt(4)" ::: "memory");
  GBAR();
  __builtin_amdgcn_sched_barrier(0);

  for (int r = 0; r < R; ++r) {
    const size_t kA1 = (size_t)(2*r + 1) * 64;
    const size_t kN  = (size_t)(2*r + 2) * 64;
    const size_t kN1 = (size_t)(2*r + 3) * 64;
    const bool more = (r + 1 < R);

    LDA_(0, 0); LDB_(0, 0);
    STAGE(Ag + kA1, 16384);
    GBAR(); MMA_(0, 0); GBAR();
    LDB_(0, 1);
    STAGE(Ag + HSTR + kA1, 16384 + 8192);
    GBAR(); MMA_(0, 1); GBAR();
    LDA_(0, 1);
    if (more) STAGE(Bg + kN, 32768);
    GBAR(); MMA_(1, 0); GBAR();
    if (more) STAGE(Bg + HSTR + kN, 32768 + 8192);
    GBAR(); MMA_(1, 1);
    if (more) asm volatile("s_waitcnt vmcnt(4)" ::: "memory");
    else      asm volatile("s_waitcnt vmcnt(0)" ::: "memory");
    GBAR();
    __builtin_amdgcn_sched_barrier(0);
    LDA_(1, 0); LDB_(1, 0);
    if (more) STAGE(Ag + kN, 0);
    GBAR(); MMA_(0, 0); GBAR();
    LDB_(1, 1);
    if (more) STAGE(Ag + HSTR + kN, 8192);
    GBAR(); MMA_(0, 1); GBAR();
    LDA_(1, 1);
    if (more) STAGE(Bg + kN1, 32768 + 16384);
    GBAR(); MMA_(1, 0); GBAR();
    if (more) STAGE(Bg + HSTR + kN1, 32768 + 16384 + 8192);
    GBAR(); MMA_(1, 1);
    if (more) asm volatile("s_waitcnt vmcnt(4)" ::: "memory");
    else      asm volatile("s_waitcnt vmcnt(0)" ::: "memory");
    GBAR();
    __builtin_amdgcn_sched_barrier(0);
  }

  const int crow0 = m0 + wm*128 + hi*4;
  const int ccol0 = n0 + wn*64 + fr;
#pragma unroll
  for (int j = 0; j < 4; ++j) {
    const int col = ccol0 + j * 16;
    const float bc = bias[col];
#pragma unroll
    for (int mi = 0; mi < 8; ++mi) {
#pragma unroll
      for (int rr = 0; rr < 4; ++rr) {
        const int row = crow0 + mi * 16 + rr;
        float v = acc[mi][j][rr] + bc;
        if (MODE == 0) {
          if (col < 2048) v = (v > 0.f) ? (v + 1.f) : __expf(v);  // elu(x)+1
          ((unsigned short*)outp)[(size_t)row * N + col] = f2bf(v);
        } else if (MODE == 1) {
          v += addsrc[(size_t)row * N + col];
          ((float*)outp)[(size_t)row * N + col] = v;
        } else {
          v = gelu_f(v);
          ((unsigned short*)outp)[(size_t)row * N + col] = f2bf(v);
        }
      }
    }
  }
#undef STAGE
#undef LDA_
#undef LDB_
#undef MMA_
#undef GBAR
}

// ---------------- MFMA per-position head-mix "attention" ---------------------
__global__ void __launch_bounds__(256) attn_kernel(
    const unsigned short* __restrict__ qkv, unsigned short* __restrict__ attn)
{
  __shared__ unsigned short kvs[4][16 * 70];  // per-wave kvT, row stride 70
  const int t = threadIdx.x, lane = t & 63, wid = t >> 6;
  const int iL = lane & 15, g = lane >> 4;
  const size_t p = (size_t)blockIdx.x * 4 + wid;
  const unsigned short* row = qkv + p * 3072;
  unsigned short* kvw = kvs[wid] + iL * 70;

  const unsigned msk = (g < 2) ? 0xFFFFFFFFu : 0u;
  bf16x8 A1[4];
#pragma unroll
  for (int dt = 0; dt < 4; ++dt) {
    u32x4 w = *(const u32x4*)(row + 1024 + (dt * 16 + iL) * 16 + g * 8);
    w.x &= msk; w.y &= msk; w.z &= msk; w.w &= msk;
    A1[dt] = __builtin_bit_cast(bf16x8, w);
  }
  bf16x8 B1[4];
#pragma unroll
  for (int et = 0; et < 4; ++et)
    B1[et] = *(const bf16x8*)(row + 2048 + (et * 16 + iL) * 16 + g * 8);
  const unsigned short* fqp = row + iL * 64 + g * 8;
  const bf16x8 aq0 = *(const bf16x8*)(fqp);
  const bf16x8 aq1 = *(const bf16x8*)(fqp + 32);
  const unsigned ow = (iL == 0 && g < 2) ? 0x3F803F80u : 0u;
  u32x4 onesw = { ow, ow, ow, ow };
  const bf16x8 Bones = __builtin_bit_cast(bf16x8, onesw);

  const f32x4 zf = {0.f, 0.f, 0.f, 0.f};
  f32x4 qacc[5];

#pragma unroll
  for (int et = 0; et < 5; ++et) {
    const bf16x8 Bt1 = (et < 4) ? B1[et] : Bones;
#pragma unroll
    for (int dt = 0; dt < 4; ++dt) {
      f32x4 a = __builtin_amdgcn_mfma_f32_16x16x32_bf16(A1[dt], Bt1, zf, 0, 0, 0);
      ushort4 pk;
      pk.x = f2bf(a[0]); pk.y = f2bf(a[1]); pk.z = f2bf(a[2]); pk.w = f2bf(a[3]);
      *(ushort4*)(kvw + dt * 16 + g * 4) = pk;   // d = dt*16 + g*4 + r
    }
    asm volatile("s_waitcnt lgkmcnt(0)" ::: "memory");
    __builtin_amdgcn_sched_barrier(0);
    const bf16x8 b20 = *(const bf16x8*)(kvw + g * 8);
    const bf16x8 b21 = *(const bf16x8*)(kvw + 32 + g * 8);
    f32x4 q = __builtin_amdgcn_mfma_f32_16x16x32_bf16(aq0, b20, zf, 0, 0, 0);
    q       = __builtin_amdgcn_mfma_f32_16x16x32_bf16(aq1, b21, q,  0, 0, 0);
    qacc[et] = q;
    asm volatile("s_waitcnt lgkmcnt(0)" ::: "memory");
    __builtin_amdgcn_sched_barrier(0);
  }

  float inv[4];
#pragma unroll
  for (int r = 0; r < 4; ++r) {
    float qk = __shfl(qacc[4][r], lane & 48);
    float den = qk + 1e-6f;
    float x = __builtin_amdgcn_rcpf(den);
    inv[r] = x * fmaf(-den, x, 2.0f);   // one NR step
  }
  u16x8 o0, o1;
#pragma unroll
  for (int r = 0; r < 4; ++r)
#pragma unroll
    for (int tt = 0; tt < 4; ++tt) {
      const unsigned short b = f2bf(qacc[tt][r] * inv[r]);
      const int idx = r * 4 + tt;      // c' = lane*16 + r*4 + tt
      if (idx < 8) o0[idx] = b; else o1[idx - 8] = b;
    }
  *(u16x8*)(attn + p * 1024 + lane * 16)     = o0;
  *(u16x8*)(attn + p * 1024 + lane * 16 + 8) = o1;
}

// ---------------- launch ----------------------------------------------------
extern "C" void kernel_launch(void* const* d_in, const int* in_sizes, int n_in,
                              void* d_out, int out_size, void* d_ws, size_t ws_size,
                              hipStream_t stream) {
  const float* q_x    = (const float*)d_in[0];
  const float* ln1_w  = (const float*)d_in[1];
  const float* ln1_b  = (const float*)d_in[2];
  const float* wq     = (const float*)d_in[3];
  const float* bq     = (const float*)d_in[4];
  const float* wk     = (const float*)d_in[5];
  const float* bk     = (const float*)d_in[6];
  const float* wv     = (const float*)d_in[7];
  const float* bv     = (const float*)d_in[8];
  const float* wo     = (const float*)d_in[9];
  const float* bo     = (const float*)d_in[10];
  const float* ln2_w  = (const float*)d_in[11];
  const float* ln2_b  = (const float*)d_in[12];
  const float* fc_w   = (const float*)d_in[13];
  const float* fc_b   = (const float*)d_in[14];
  const float* proj_w = (const float*)d_in[15];
  const float* proj_b = (const float*)d_in[16];

  char* ws = (char*)d_ws;
  unsigned short* wqkv_t = (unsigned short*)(ws + 0);          //  [3072][1024]
  unsigned short* wo_t   = (unsigned short*)(ws + 6291456);    //  [1024][1024] (permc'd K)
  unsigned short* fc_t   = (unsigned short*)(ws + 8388608);    //  [4096][1024]
  unsigned short* proj_t = (unsigned short*)(ws + 16777216);   //  [1024][4096]
  float*          bqkv   = (float*)(ws + 25165824);            //  [3072]
  unsigned short* xn     = (unsigned short*)(ws + 25178112);   //  [16384][1024]
  unsigned short* big    = (unsigned short*)(ws + 58732544);   //  qkv/hg
  float*          xres   = (float*)d_out;

  dim3 blk(256);
  transpose_cvt<0><<<dim3(32, 32),  blk, 0, stream>>>(wq,     wqkv_t,           1024, 1024);
  transpose_cvt<2><<<dim3(32, 32),  blk, 0, stream>>>(wk,     wqkv_t + 1048576, 1024, 1024);
  transpose_cvt<2><<<dim3(32, 32),  blk, 0, stream>>>(wv,     wqkv_t + 2097152, 1024, 1024);
  transpose_cvt<1><<<dim3(32, 32),  blk, 0, stream>>>(wo,     wo_t,             1024, 1024);
  transpose_cvt<0><<<dim3(128, 32), blk, 0, stream>>>(fc_w,   fc_t,             1024, 4096);
  transpose_cvt<0><<<dim3(32, 128), blk, 0, stream>>>(proj_w, proj_t,           4096, 1024);
  concat_bias<<<12, blk, 0, stream>>>(bq, bk, bv, bqkv);

  ln_kernel<<<NTOK, blk, 0, stream>>>(q_x, ln1_w, ln1_b, xn);
  gemm256<0><<<64 * 12, 512, 131072, stream>>>(xn, wqkv_t, NTOK, 3072, 1024, bqkv, nullptr, big);
  attn_kernel<<<NTOK / 4, blk, 0, stream>>>(big, xn);
  gemm256<1><<<64 * 4,  512, 131072, stream>>>(xn, wo_t,   NTOK, 1024, 1024, bo, q_x, xres);
  ln_kernel<<<NTOK, blk, 0, stream>>>(xres, ln2_w, ln2_b, xn);
  gemm256<2><<<64 * 16, 512, 131072, stream>>>(xn, fc_t,   NTOK, 4096, 1024, fc_b, nullptr, big);
  gemm256<1><<<64 * 4,  512, 131072, stream>>>(big, proj_t, NTOK, 1024, 4096, proj_b, xres, xres);
}

// Round 6
// 692.930 us; speedup vs baseline: 1.1711x; 1.1711x over previous
//
#include <hip/hip_runtime.h>
#include <hip/hip_bf16.h>
#include <math.h>

// Problem constants: B=4, N=4096, D=1024, H=16, HD=64, MLP=4096
#define NTOK   16384      // B*N rows
#define DMODEL 1024
#define DMLP   4096

typedef __attribute__((ext_vector_type(8))) __bf16  bf16x8;
typedef __attribute__((ext_vector_type(4))) float   f32x4;
typedef __attribute__((ext_vector_type(8))) unsigned short u16x8;
typedef __attribute__((ext_vector_type(4))) unsigned int   u32x4;

__device__ __forceinline__ float bf2f(unsigned short u) {
  unsigned int i = ((unsigned int)u) << 16;
  return __builtin_bit_cast(float, i);
}
__device__ __forceinline__ unsigned short f2bf(float f) {
  unsigned int u = __builtin_bit_cast(unsigned int, f);
  unsigned int r = 0x7fffu + ((u >> 16) & 1u);
  return (unsigned short)((u + r) >> 16);
}

__device__ __forceinline__ void gload_lds16(const void* g, void* l) {
  __builtin_amdgcn_global_load_lds(
      (const __attribute__((address_space(1))) unsigned int*)g,
      (__attribute__((address_space(3))) unsigned int*)l, 16, 0, 0);
}

__device__ __forceinline__ float gelu_f(float x) {
  float u = 1.5957691216057308f * (x + 0.044715f * x * x * x);
  return x / (1.f + __expf(-u));
}

// attn-output column permutation: c = g(2):r(2):t(2):i(4) -> c' = g:i:r:t
__device__ __forceinline__ int permc(int k) {
  return (k & 0x300) | ((k & 15) << 4) | (((k >> 6) & 3) << 2) | ((k >> 4) & 3);
}
// qkv k/v-block column permutation: n = h*64+d -> n' = d*16+h  (within 1024 block)
__device__ __forceinline__ int kvperm(int n) {
  return ((n & 63) << 4) | ((n >> 6) & 15);
}

// ---------------- weight transpose + f32->bf16 -------------------------------
// PERM: 0 none; 1 = permc on K index (wo); 2 = kvperm on N index (wk/wv)
template<int PERM>
__global__ void __launch_bounds__(256) transpose_cvt(
    const float* __restrict__ W, unsigned short* __restrict__ Wt, int K, int N)
{
  __shared__ float tile[32][33];
  const int kb = blockIdx.y * 32, nb = blockIdx.x * 32;
  const int tx = threadIdx.x & 31, ty = threadIdx.x >> 5;   // 32 x 8
#pragma unroll
  for (int j = 0; j < 32; j += 8)
    tile[ty + j][tx] = W[(size_t)(kb + ty + j) * N + nb + tx];
  __syncthreads();
  const int kw = (PERM == 1) ? permc(kb + tx) : (kb + tx);
#pragma unroll
  for (int j = 0; j < 32; j += 8) {
    const int n  = nb + ty + j;
    const int nw = (PERM == 2) ? kvperm(n) : n;
    Wt[(size_t)nw * K + kw] = f2bf(tile[tx][ty + j]);
  }
}

__global__ void __launch_bounds__(256) concat_bias(
    const float* __restrict__ bq, const float* __restrict__ bk,
    const float* __restrict__ bv, float* __restrict__ bqkv)
{
  const int i = blockIdx.x * 256 + threadIdx.x;   // grid 12 -> 3072
  if (i < 1024)      bqkv[i] = bq[i];
  else if (i < 2048) bqkv[1024 + kvperm(i - 1024)] = bk[i - 1024];
  else               bqkv[2048 + kvperm(i - 2048)] = bv[i - 2048];
}

// ---------------- LayerNorm (biased var, eps=1e-5) -> bf16 -------------------
__global__ void __launch_bounds__(256) ln_kernel(
    const float* __restrict__ x, const float* __restrict__ w,
    const float* __restrict__ b, unsigned short* __restrict__ out)
{
  const int row = blockIdx.x;
  const int t = threadIdx.x;
  const float4 v = ((const float4*)(x + (size_t)row * DMODEL))[t];
  float s  = v.x + v.y + v.z + v.w;
  float s2 = v.x*v.x + v.y*v.y + v.z*v.z + v.w*v.w;
#pragma unroll
  for (int o = 1; o < 64; o <<= 1) { s += __shfl_xor(s, o); s2 += __shfl_xor(s2, o); }
  __shared__ float red[8];
  const int wid = t >> 6;
  if ((t & 63) == 0) { red[wid] = s; red[4 + wid] = s2; }
  __syncthreads();
  s  = red[0] + red[1] + red[2] + red[3];
  s2 = red[4] + red[5] + red[6] + red[7];
  const float mean = s * (1.f / DMODEL);
  const float rstd = rsqrtf(s2 * (1.f / DMODEL) - mean * mean + 1e-5f);
  const float4 wv = ((const float4*)w)[t];
  const float4 bv = ((const float4*)b)[t];
  ushort4 o;
  o.x = f2bf((v.x - mean) * rstd * wv.x + bv.x);
  o.y = f2bf((v.y - mean) * rstd * wv.y + bv.y);
  o.z = f2bf((v.z - mean) * rstd * wv.z + bv.z);
  o.w = f2bf((v.w - mean) * rstd * wv.w + bv.w);
  ((ushort4*)(out + (size_t)row * DMODEL))[t] = o;
}

// ---------------- 256x256 8-phase bf16 MFMA GEMM -----------------------------
// Schedule identical to the verified round-2/4 kernel; supertile mapping from
// round 5; NEW this round: j-innermost epilogue so each 128-B output line is
// completed by 4 back-to-back sector stores (kills partial-line re-writeback).
template<int MODE>
__global__ void __launch_bounds__(512, 2) gemm256(
    const unsigned short* __restrict__ A, const unsigned short* __restrict__ Bt,
    int M, int N, int K,
    const float* __restrict__ bias, const float* __restrict__ addsrc,
    void* __restrict__ outp)
{
  extern __shared__ unsigned short lds[];   // 65536 shorts = 128 KiB
  const int t    = threadIdx.x;
  const int lane = t & 63;
  const int wid  = t >> 6;
  const int wm   = wid >> 2;     // 0..1
  const int wn   = wid & 3;      // 0..3
  const int fr   = lane & 15;
  const int hi   = lane >> 4;    // 0..3

  const int tiles_n = N >> 8;
  const int nwg = (int)gridDim.x;
  const int cpx = nwg >> 3;
  const int bid = (int)blockIdx.x;
  const int wg  = (bid & 7) * cpx + (bid >> 3);   // XCD-chunked
  // 4x4 super-tile within the chunk
  const int grp = wg >> 4, in16 = wg & 15;
  const int gpr = tiles_n >> 2;
  const int mt  = (grp / gpr) * 4 + (in16 >> 2);
  const int nt  = (grp % gpr) * 4 + (in16 & 3);
  const int m0 = mt << 8;
  const int n0 = nt << 8;

  const int srow0 = t >> 3;
  const int srow1 = srow0 + 64;
  const int sc    = t & 7;
  const size_t soff0 = (size_t)srow0 * K + (size_t)((sc ^ (srow0 & 7)) << 3);
  const size_t soff1 = (size_t)srow1 * K + (size_t)((sc ^ (srow1 & 7)) << 3);
  const unsigned short* Ag = A  + (size_t)m0 * K;
  const unsigned short* Bg = Bt + (size_t)n0 * K;

  const int pc0 = hi ^ (fr & 7);         // ks=0 chunk
  const int pc1 = (4 + hi) ^ (fr & 7);   // ks=1 chunk

  f32x4  acc[8][4] = {};
  bf16x8 af[4][2];
  bf16x8 bfr[4][2];

#define STAGE(gptr, ro) do { \
    gload_lds16((gptr) + soff0, lds + (ro) + t*8); \
    gload_lds16((gptr) + soff1, lds + (ro) + 4096 + t*8); \
  } while(0)

#define LDA_(buf, mh) do { \
    const unsigned short* p_ = lds + (buf)*16384 + wm*8192 + (mh)*4096 + fr*64; \
    _Pragma("unroll") for (int i = 0; i < 4; ++i) { \
      af[i][0] = *(const bf16x8*)(p_ + i*1024 + pc0*8); \
      af[i][1] = *(const bf16x8*)(p_ + i*1024 + pc1*8); } \
  } while(0)

#define LDB_(buf, nh) do { \
    const unsigned short* p_ = lds + 32768 + (buf)*16384 + (wn>>1)*8192 + (wn&1)*4096 + fr*64; \
    _Pragma("unroll") for (int jj = 0; jj < 2; ++jj) { \
      bfr[(nh)*2+jj][0] = *(const bf16x8*)(p_ + ((nh)*2+jj)*1024 + pc0*8); \
      bfr[(nh)*2+jj][1] = *(const bf16x8*)(p_ + ((nh)*2+jj)*1024 + pc1*8); } \
  } while(0)

#define MMA_(mh, nh) do { \
    __builtin_amdgcn_s_setprio(1); \
    _Pragma("unroll") for (int i = 0; i < 4; ++i) \
      _Pragma("unroll") for (int jj = 0; jj < 2; ++jj) { \
        acc[(mh)*4+i][(nh)*2+jj] = __builtin_amdgcn_mfma_f32_16x16x32_bf16(af[i][0], bfr[(nh)*2+jj][0], acc[(mh)*4+i][(nh)*2+jj], 0,0,0); \
        acc[(mh)*4+i][(nh)*2+jj] = __builtin_amdgcn_mfma_f32_16x16x32_bf16(af[i][1], bfr[(nh)*2+jj][1], acc[(mh)*4+i][(nh)*2+jj], 0,0,0); } \
    __builtin_amdgcn_s_setprio(0); \
  } while(0)

#define GBAR() __builtin_amdgcn_s_barrier()

  const size_t HSTR = (size_t)128 * K;
  const int NT = K >> 6;
  const int R  = NT >> 1;

  STAGE(Ag,               0);
  STAGE(Ag + HSTR,        8192);
  STAGE(Bg,               32768);
  STAGE(Bg + HSTR,        32768 + 8192);
  STAGE(Bg + 64,          32768 + 16384);
  STAGE(Bg + HSTR + 64,   32768 + 16384 + 8192);
  asm volatile("s_waitcnt vmcnt(4)" ::: "memory");
  GBAR();
  __builtin_amdgcn_sched_barrier(0);

  for (int r = 0; r < R; ++r) {
    const size_t kA1 = (size_t)(2*r + 1) * 64;
    const size_t kN  = (size_t)(2*r + 2) * 64;
    const size_t kN1 = (size_t)(2*r + 3) * 64;
    const bool more = (r + 1 < R);

    LDA_(0, 0); LDB_(0, 0);
    STAGE(Ag + kA1, 16384);
    GBAR(); MMA_(0, 0); GBAR();
    LDB_(0, 1);
    STAGE(Ag + HSTR + kA1, 16384 + 8192);
    GBAR(); MMA_(0, 1); GBAR();
    LDA_(0, 1);
    if (more) STAGE(Bg + kN, 32768);
    GBAR(); MMA_(1, 0); GBAR();
    if (more) STAGE(Bg + HSTR + kN, 32768 + 8192);
    GBAR(); MMA_(1, 1);
    if (more) asm volatile("s_waitcnt vmcnt(4)" ::: "memory");
    else      asm volatile("s_waitcnt vmcnt(0)" ::: "memory");
    GBAR();
    __builtin_amdgcn_sched_barrier(0);
    LDA_(1, 0); LDB_(1, 0);
    if (more) STAGE(Ag + kN, 0);
    GBAR(); MMA_(0, 0); GBAR();
    LDB_(1, 1);
    if (more) STAGE(Ag + HSTR + kN, 8192);
    GBAR(); MMA_(0, 1); GBAR();
    LDA_(1, 1);
    if (more) STAGE(Bg + kN1, 32768 + 16384);
    GBAR(); MMA_(1, 0); GBAR();
    if (more) STAGE(Bg + HSTR + kN1, 32768 + 16384 + 8192);
    GBAR(); MMA_(1, 1);
    if (more) asm volatile("s_waitcnt vmcnt(4)" ::: "memory");
    else      asm volatile("s_waitcnt vmcnt(0)" ::: "memory");
    GBAR();
    __builtin_amdgcn_sched_barrier(0);
  }

  // epilogue: row = m0+wm*128+mi*16+hi*4+rr ; col = n0+wn*64+j*16+fr.
  // j INNERMOST: the 4 sector stores of each touched 128-B line are adjacent.
  const int crow0 = m0 + wm*128 + hi*4;
  const int ccol0 = n0 + wn*64 + fr;
  float bc4[4];
#pragma unroll
  for (int j = 0; j < 4; ++j) bc4[j] = bias[ccol0 + j * 16];
#pragma unroll
  for (int mi = 0; mi < 8; ++mi) {
#pragma unroll
    for (int rr = 0; rr < 4; ++rr) {
      const int row = crow0 + mi * 16 + rr;
#pragma unroll
      for (int j = 0; j < 4; ++j) {
        const int col = ccol0 + j * 16;
        float v = acc[mi][j][rr] + bc4[j];
        if (MODE == 0) {
          if (col < 2048) v = (v > 0.f) ? (v + 1.f) : __expf(v);  // elu(x)+1
          ((unsigned short*)outp)[(size_t)row * N + col] = f2bf(v);
        } else if (MODE == 1) {
          v += addsrc[(size_t)row * N + col];
          ((float*)outp)[(size_t)row * N + col] = v;
        } else {
          v = gelu_f(v);
          ((unsigned short*)outp)[(size_t)row * N + col] = f2bf(v);
        }
      }
    }
  }
#undef STAGE
#undef LDA_
#undef LDB_
#undef MMA_
#undef GBAR
}

// ---------------- MFMA per-position head-mix "attention" ---------------------
__global__ void __launch_bounds__(256) attn_kernel(
    const unsigned short* __restrict__ qkv, unsigned short* __restrict__ attn)
{
  __shared__ unsigned short kvs[4][16 * 70];  // per-wave kvT, row stride 70
  const int t = threadIdx.x, lane = t & 63, wid = t >> 6;
  const int iL = lane & 15, g = lane >> 4;
  const size_t p = (size_t)blockIdx.x * 4 + wid;
  const unsigned short* row = qkv + p * 3072;
  unsigned short* kvw = kvs[wid] + iL * 70;

  const unsigned msk = (g < 2) ? 0xFFFFFFFFu : 0u;
  bf16x8 A1[4];
#pragma unroll
  for (int dt = 0; dt < 4; ++dt) {
    u32x4 w = *(const u32x4*)(row + 1024 + (dt * 16 + iL) * 16 + g * 8);
    w.x &= msk; w.y &= msk; w.z &= msk; w.w &= msk;
    A1[dt] = __builtin_bit_cast(bf16x8, w);
  }
  bf16x8 B1[4];
#pragma unroll
  for (int et = 0; et < 4; ++et)
    B1[et] = *(const bf16x8*)(row + 2048 + (et * 16 + iL) * 16 + g * 8);
  const unsigned short* fqp = row + iL * 64 + g * 8;
  const bf16x8 aq0 = *(const bf16x8*)(fqp);
  const bf16x8 aq1 = *(const bf16x8*)(fqp + 32);
  const unsigned ow = (iL == 0 && g < 2) ? 0x3F803F80u : 0u;
  u32x4 onesw = { ow, ow, ow, ow };
  const bf16x8 Bones = __builtin_bit_cast(bf16x8, onesw);

  const f32x4 zf = {0.f, 0.f, 0.f, 0.f};
  f32x4 qacc[5];

#pragma unroll
  for (int et = 0; et < 5; ++et) {
    const bf16x8 Bt1 = (et < 4) ? B1[et] : Bones;
#pragma unroll
    for (int dt = 0; dt < 4; ++dt) {
      f32x4 a = __builtin_amdgcn_mfma_f32_16x16x32_bf16(A1[dt], Bt1, zf, 0, 0, 0);
      ushort4 pk;
      pk.x = f2bf(a[0]); pk.y = f2bf(a[1]); pk.z = f2bf(a[2]); pk.w = f2bf(a[3]);
      *(ushort4*)(kvw + dt * 16 + g * 4) = pk;   // d = dt*16 + g*4 + r
    }
    asm volatile("s_waitcnt lgkmcnt(0)" ::: "memory");
    __builtin_amdgcn_sched_barrier(0);
    const bf16x8 b20 = *(const bf16x8*)(kvw + g * 8);
    const bf16x8 b21 = *(const bf16x8*)(kvw + 32 + g * 8);
    f32x4 q = __builtin_amdgcn_mfma_f32_16x16x32_bf16(aq0, b20, zf, 0, 0, 0);
    q       = __builtin_amdgcn_mfma_f32_16x16x32_bf16(aq1, b21, q,  0, 0, 0);
    qacc[et] = q;
    asm volatile("s_waitcnt lgkmcnt(0)" ::: "memory");
    __builtin_amdgcn_sched_barrier(0);
  }

  float inv[4];
#pragma unroll
  for (int r = 0; r < 4; ++r) {
    float qk = __shfl(qacc[4][r], lane & 48);
    float den = qk + 1e-6f;
    float x = __builtin_amdgcn_rcpf(den);
    inv[r] = x * fmaf(-den, x, 2.0f);   // one NR step
  }
  u16x8 o0, o1;
#pragma unroll
  for (int r = 0; r < 4; ++r)
#pragma unroll
    for (int tt = 0; tt < 4; ++tt) {
      const unsigned short b = f2bf(qacc[tt][r] * inv[r]);
      const int idx = r * 4 + tt;      // c' = lane*16 + r*4 + tt
      if (idx < 8) o0[idx] = b; else o1[idx - 8] = b;
    }
  *(u16x8*)(attn + p * 1024 + lane * 16)     = o0;
  *(u16x8*)(attn + p * 1024 + lane * 16 + 8) = o1;
}

// ---------------- launch ----------------------------------------------------
extern "C" void kernel_launch(void* const* d_in, const int* in_sizes, int n_in,
                              void* d_out, int out_size, void* d_ws, size_t ws_size,
                              hipStream_t stream) {
  const float* q_x    = (const float*)d_in[0];
  const float* ln1_w  = (const float*)d_in[1];
  const float* ln1_b  = (const float*)d_in[2];
  const float* wq     = (const float*)d_in[3];
  const float* bq     = (const float*)d_in[4];
  const float* wk     = (const float*)d_in[5];
  const float* bk     = (const float*)d_in[6];
  const float* wv     = (const float*)d_in[7];
  const float* bv     = (const float*)d_in[8];
  const float* wo     = (const float*)d_in[9];
  const float* bo     = (const float*)d_in[10];
  const float* ln2_w  = (const float*)d_in[11];
  const float* ln2_b  = (const float*)d_in[12];
  const float* fc_w   = (const float*)d_in[13];
  const float* fc_b   = (const float*)d_in[14];
  const float* proj_w = (const float*)d_in[15];
  const float* proj_b = (const float*)d_in[16];

  char* ws = (char*)d_ws;
  unsigned short* wqkv_t = (unsigned short*)(ws + 0);          //  [3072][1024]
  unsigned short* wo_t   = (unsigned short*)(ws + 6291456);    //  [1024][1024] (permc'd K)
  unsigned short* fc_t   = (unsigned short*)(ws + 8388608);    //  [4096][1024]
  unsigned short* proj_t = (unsigned short*)(ws + 16777216);   //  [1024][4096]
  float*          bqkv   = (float*)(ws + 25165824);            //  [3072]
  unsigned short* xn     = (unsigned short*)(ws + 25178112);   //  [16384][1024]
  unsigned short* big    = (unsigned short*)(ws + 58732544);   //  qkv/hg
  float*          xres   = (float*)d_out;

  dim3 blk(256);
  transpose_cvt<0><<<dim3(32, 32),  blk, 0, stream>>>(wq,     wqkv_t,           1024, 1024);
  transpose_cvt<2><<<dim3(32, 32),  blk, 0, stream>>>(wk,     wqkv_t + 1048576, 1024, 1024);
  transpose_cvt<2><<<dim3(32, 32),  blk, 0, stream>>>(wv,     wqkv_t + 2097152, 1024, 1024);
  transpose_cvt<1><<<dim3(32, 32),  blk, 0, stream>>>(wo,     wo_t,             1024, 1024);
  transpose_cvt<0><<<dim3(128, 32), blk, 0, stream>>>(fc_w,   fc_t,             1024, 4096);
  transpose_cvt<0><<<dim3(32, 128), blk, 0, stream>>>(proj_w, proj_t,           4096, 1024);
  concat_bias<<<12, blk, 0, stream>>>(bq, bk, bv, bqkv);

  ln_kernel<<<NTOK, blk, 0, stream>>>(q_x, ln1_w, ln1_b, xn);
  gemm256<0><<<64 * 12, 512, 131072, stream>>>(xn, wqkv_t, NTOK, 3072, 1024, bqkv, nullptr, big);
  attn_kernel<<<NTOK / 4, blk, 0, stream>>>(big, xn);
  gemm256<1><<<64 * 4,  512, 131072, stream>>>(xn, wo_t,   NTOK, 1024, 1024, bo, q_x, xres);
  ln_kernel<<<NTOK, blk, 0, stream>>>(xres, ln2_w, ln2_b, xn);
  gemm256<2><<<64 * 16, 512, 131072, stream>>>(xn, fc_t,   NTOK, 4096, 1024, fc_b, nullptr, big);
  gemm256<1><<<64 * 4,  512, 131072, stream>>>(big, proj_t, NTOK, 1024, 4096, proj_b, xres, xres);
}